// Round 2
// baseline (2926.160 us; speedup 1.0000x reference)
//
#include <hip/hip_runtime.h>

// Q4_0 SwiGLU FFN, MI355X. dim=4096, hidden=11008, M=4096 tokens.
// Round 2: fuse dequant into GEMM B-staging to shrink workspace 394MB -> 124MB
// (round-1 fault attributed to d_ws overflow).
//   K1: x -> bf16 (Xb)
//   K2: G = X*W3^T            (dequant-fused GEMM, bf16 out)
//   K3: G = silu(X*W1^T) * G  (dequant-fused GEMM, in-place SwiGLU epilogue)
//   K4: out = G*W2^T          (dequant-fused GEMM, f32 out)

typedef __bf16 bf16;
typedef __bf16 bf16x4 __attribute__((ext_vector_type(4)));
typedef __bf16 bf16x8 __attribute__((ext_vector_type(8)));
typedef float  f32x4  __attribute__((ext_vector_type(4)));

#define BM 128
#define BN 128
#define BK 32
#define BSTR 40  // Bs row stride (bf16): 80B rows -> 2-way (free) read conflicts, 16B aligned

__device__ __forceinline__ void gload_lds16(const bf16* g, bf16* l) {
  __builtin_amdgcn_global_load_lds(
      (__attribute__((address_space(1))) void*)(g),
      (__attribute__((address_space(3))) void*)(l), 16, 0, 0);
}

// ------------------------------------------------------------- x -> bf16 ---
__global__ void f32_to_bf16_k(const float* __restrict__ x,
                              bf16* __restrict__ y, int n4) {
  int t = blockIdx.x * blockDim.x + threadIdx.x;
  if (t >= n4) return;
  float4 v = ((const float4*)x)[t];
  bf16x4 o;
  o[0] = (bf16)v.x; o[1] = (bf16)v.y; o[2] = (bf16)v.z; o[3] = (bf16)v.w;
  ((bf16x4*)y)[t] = o;
}

// ------------------------------------------------ dequant-fused GEMM (B^T) --
// C(MxN) = A(MxK) * W(NxK)^T.  W given packed Q4_0: int32 array, one byte per
// int32; weight row n, element k lives at packed index n*(K/2) + (k>>7)*64 +
// (k&63); msb nibble if (k&127)<64 else lsb; scale s[(n*K+k)>>6].
// EPI: 0 = f32 store, 1 = bf16 store, 2 = G = silu(acc)*G in place (bf16).
template <int EPI>
__launch_bounds__(256)
__global__ void gemm_dq_k(const bf16* __restrict__ A,
                          const int* __restrict__ Wq,
                          const float* __restrict__ S,
                          bf16* __restrict__ G,
                          float* __restrict__ Fout,
                          int M, int N, int K) {
  __shared__ __attribute__((aligned(16))) bf16 As[BM * BK];    // 8 KB
  __shared__ __attribute__((aligned(16))) bf16 Bs[BN * BSTR];  // 10 KB

  const int tid  = threadIdx.x;
  const int lane = tid & 63;
  const int wave = tid >> 6;
  const int n0 = blockIdx.x * BN;
  const int m0 = blockIdx.y * BM;

  // --- A staging (m97): 128x32 bf16 tile = 8192B, thread covers 2 x 16B.
  const int o0 = tid * 16, o1 = tid * 16 + 4096;
  const bf16* a0 = A + (size_t)(m0 + (o0 >> 6)) * K + ((o0 & 63) >> 1);
  const bf16* a1 = A + (size_t)(m0 + (o1 >> 6)) * K + ((o1 & 63) >> 1);
  bf16* lA0 = As + (o0 >> 1);
  bf16* lA1 = As + (o1 >> 1);

  // --- B dequant staging: thread -> (row rr, 16-wide k-segment seg).
  const int rr  = tid >> 1;
  const int seg = (tid & 1) * 16;
  const int nrow = n0 + rr;
  const int K2 = K >> 1;  // int32s per weight row
  const int* wrow = Wq + (size_t)nrow * K2;
  const float* srow = S + (size_t)nrow * (K >> 6);
  bf16* bdst = Bs + rr * BSTR + seg;

  // --- fragment addressing
  const int fm = lane & 15;
  const int fq = lane >> 4;
  const int wm = (wave >> 1) * 64;
  const int wn = (wave & 1) * 64;

  f32x4 acc[4][4] = {};

  for (int k0 = 0; k0 < K; k0 += BK) {
    // A -> LDS (async DMA)
    gload_lds16(a0, lA0);
    gload_lds16(a1, lA1);
    a0 += BK; a1 += BK;

    // W packed -> registers -> dequant -> LDS
    const int kk = k0 + seg;
    const int* wp = wrow + ((kk >> 7) << 6) + (kk & 63);
    int4 q0 = ((const int4*)wp)[0];
    int4 q1 = ((const int4*)wp)[1];
    int4 q2 = ((const int4*)wp)[2];
    int4 q3 = ((const int4*)wp)[3];
    const float sc = srow[kk >> 6];
    const int sh = ((kk & 127) < 64) ? 4 : 0;
    int qa[16] = {q0.x, q0.y, q0.z, q0.w, q1.x, q1.y, q1.z, q1.w,
                  q2.x, q2.y, q2.z, q2.w, q3.x, q3.y, q3.z, q3.w};
    bf16x8 lo, hi;
#pragma unroll
    for (int i = 0; i < 16; i++) {
      int v = (((qa[i] >> sh) & 0xF) ^ 8) - 8;  // signed nibble [-8,8)
      float f = (float)v * sc;
      if (i < 8) lo[i] = (bf16)f;
      else       hi[i - 8] = (bf16)f;
    }
    *(bf16x8*)(bdst)     = lo;
    *(bf16x8*)(bdst + 8) = hi;

    __syncthreads();

    bf16x8 af[4], bfr[4];
#pragma unroll
    for (int i = 0; i < 4; i++)
      af[i] = *(const bf16x8*)&As[(wm + 16 * i + fm) * BK + fq * 8];
#pragma unroll
    for (int j = 0; j < 4; j++)
      bfr[j] = *(const bf16x8*)&Bs[(wn + 16 * j + fm) * BSTR + fq * 8];

#pragma unroll
    for (int i = 0; i < 4; i++)
#pragma unroll
      for (int j = 0; j < 4; j++)
        acc[i][j] = __builtin_amdgcn_mfma_f32_16x16x32_bf16(
            af[i], bfr[j], acc[i][j], 0, 0, 0);

    __syncthreads();
  }

  // --- epilogue. C/D layout: col = lane&15, row = fq*4 + reg.
#pragma unroll
  for (int i = 0; i < 4; i++) {
    const int row0 = m0 + wm + 16 * i + fq * 4;
#pragma unroll
    for (int j = 0; j < 4; j++) {
      const int col = n0 + wn + 16 * j + fm;
#pragma unroll
      for (int r = 0; r < 4; r++) {
        size_t idx = (size_t)(row0 + r) * N + col;
        if constexpr (EPI == 0) {
          Fout[idx] = acc[i][j][r];
        } else if constexpr (EPI == 1) {
          G[idx] = (bf16)acc[i][j][r];
        } else {
          float a = acc[i][j][r];
          float g = (float)G[idx];
          G[idx] = (bf16)((a / (1.0f + __expf(-a))) * g);
        }
      }
    }
  }
}

// ------------------------------------------------------------------ launch --
extern "C" void kernel_launch(void* const* d_in, const int* in_sizes, int n_in,
                              void* d_out, int out_size, void* d_ws,
                              size_t ws_size, hipStream_t stream) {
  const float* x  = (const float*)d_in[0];
  const int*   w1 = (const int*)d_in[1];
  const float* s1 = (const float*)d_in[2];
  const int*   w2 = (const int*)d_in[3];
  const float* s2 = (const float*)d_in[4];
  const int*   w3 = (const int*)d_in[5];
  const float* s3 = (const float*)d_in[6];
  float* out = (float*)d_out;

  const int dim = 4096, hidden = 11008;
  const int M = in_sizes[0] / dim;  // 4096

  // workspace: Xb (33.5 MB) + G (90.2 MB) = 123.7 MB total
  char* ws = (char*)d_ws;
  bf16* Xb = (bf16*)ws;
  bf16* G  = (bf16*)(ws + (size_t)M * dim * 2);

  const int nx4 = M * dim / 4;
  f32_to_bf16_k<<<(nx4 + 255) / 256, 256, 0, stream>>>(x, Xb, nx4);

  dim3 gh(hidden / BN, M / BM);  // (86, 32)
  // G = X * W3^T
  gemm_dq_k<1><<<gh, 256, 0, stream>>>(Xb, w3, s3, G, nullptr, M, hidden, dim);
  // G = silu(X * W1^T) * G   (in place)
  gemm_dq_k<2><<<gh, 256, 0, stream>>>(Xb, w1, s1, G, nullptr, M, hidden, dim);

  dim3 gd(dim / BN, M / BM);     // (32, 32)
  // out = G * W2^T  (f32)
  gemm_dq_k<0><<<gd, 256, 0, stream>>>(G, w2, s2, nullptr, out, M, dim, hidden);
}